// Round 11
// baseline (223.153 us; speedup 1.0000x reference)
//
#include <hip/hip_runtime.h>

#define NSWEEP 2

typedef float v2f __attribute__((ext_vector_type(2)));

// Canonical wave64 inclusive prefix-sum (AMD GCN scan sequence).
// row_shr:1/2/4/8 within 16-lane rows (bound_ctrl zero-fills), then
// row_bcast15 (0x142, row_mask 0xA) and row_bcast31 (0x143, row_mask 0xC).
__device__ __forceinline__ float scan64(float d) {
    d += __int_as_float(__builtin_amdgcn_update_dpp(0, __float_as_int(d), 0x111, 0xF, 0xF, true));
    d += __int_as_float(__builtin_amdgcn_update_dpp(0, __float_as_int(d), 0x112, 0xF, 0xF, true));
    d += __int_as_float(__builtin_amdgcn_update_dpp(0, __float_as_int(d), 0x114, 0xF, 0xF, true));
    d += __int_as_float(__builtin_amdgcn_update_dpp(0, __float_as_int(d), 0x118, 0xF, 0xF, true));
    d += __int_as_float(__builtin_amdgcn_update_dpp(0, __float_as_int(d), 0x142, 0xA, 0xF, true));
    d += __int_as_float(__builtin_amdgcn_update_dpp(0, __float_as_int(d), 0x143, 0xC, 0xF, true));
    return d;
}

// wave-uniform broadcast of lane 63 (no LDS round-trip)
__device__ __forceinline__ float rdl63(float v) {
    return __int_as_float(__builtin_amdgcn_readlane(__float_as_int(v), 63));
}

__global__ __launch_bounds__(128, 8) void ode_wf128(
    const float* __restrict__ thr,   // B x (N+1)
    const float* __restrict__ DOD,   // B
    const float* __restrict__ Vav,   // B
    const float* __restrict__ C0,    // B
    const float* __restrict__ R0,    // B
    const float* __restrict__ W1,    // 10 x 5
    const float* __restrict__ b1,    // 10
    const float* __restrict__ W2,    // 5 x 10
    const float* __restrict__ b2,    // 5
    float* __restrict__ out,         // B x (N+1) x 2
    int B, int N)
{
    const int tid = threadIdx.x;        // 0..127
    const int w   = tid >> 6;           // wave id: lower/upper 64 steps
    const int q   = tid;                // step-slot within a 128-step block
    const int row = blockIdx.x;         // 1 row per 2-wave workgroup
    if (row >= B) return;               // uniform per workgroup

    __shared__ float s_tot[NSWEEP][2];  // wave0 scan totals, per sweep
    __shared__ float s_carry[4];        // wave1 -> all: S3g,S4g,F3,F4 at step 127

    // tanh(p) = 1 - 2/(1+e^{2p}); fold 2*log2(e) into layer-1 so exp2 applies
    // directly, fold "+1" into c3/c4 and "-2" into wa/wb. Hidden units packed
    // (h, h+5) -> v_pk_* fp32. Weight indices are wave-uniform -> SGPRs.
    const float k2 = 2.0f * 1.4426950408889634f;
    const float dod = DOD[row], vav = Vav[row];

    v2f bw[5], w0k[5], w3k[5], w4k[5], wa[5], wb[5];
    float c3 = b2[3], c4 = b2[4];
#pragma unroll
    for (int i = 0; i < 5; ++i) {
#pragma unroll
        for (int p = 0; p < 2; ++p) {
            int h = i + 5 * p;
            float a0 = W1[h * 5 + 0];
            float a1 = W1[h * 5 + 1];
            float a2 = W1[h * 5 + 2];
            float a3 = W1[h * 5 + 3];
            float a4 = W1[h * 5 + 4];
            bw[i][p]  = k2 * (b1[h] + a1 * dod + a2 * vav);
            w0k[i][p] = k2 * a0;
            w3k[i][p] = k2 * a3;
            w4k[i][p] = k2 * a4;
            float v3 = W2[30 + h];
            float v4 = W2[40 + h];
            c3 += v3; c4 += v4;
            wa[i][p] = -2.0f * v3;
            wb[i][p] = -2.0f * v4;
        }
    }

    float y03 = C0[row], y04 = R0[row];          // state entering current block
    const float* trp = thr + (size_t)row * (size_t)(N + 1);
    float2* orow = (float2*)(out + (size_t)row * (size_t)(N + 1) * 2);
    if (tid == 0) orow[0] = make_float2(y03, y04);

    // t for block 0 (coalesced across the workgroup) + block-base t
    float tq  = trp[min(q, N)];
    float tq1 = trp[min(q + 1, N)];
    float t0  = trp[0];

    // bootstrap slope F(y0, t0) — uniform across all 128 lanes
    float F3p, F4p;
    {
        v2f Fa = {c3, 0.f}, Fb = {c4, 0.f};
#pragma unroll
        for (int i = 0; i < 5; ++i) {
            v2f x = w3k[i] * y03 + (w4k[i] * y04 + (w0k[i] * t0 + bw[i]));
            v2f e; e.x = __builtin_amdgcn_exp2f(x.x); e.y = __builtin_amdgcn_exp2f(x.y);
            v2f A = e + 1.0f;
            v2f s; s.x = __builtin_amdgcn_rcpf(A.x); s.y = __builtin_amdgcn_rcpf(A.y);
            Fa += wa[i] * s;
            Fb += wb[i] * s;
        }
        F3p = Fa.x + Fa.y; F4p = Fb.x + Fb.y;
    }
    float dF3 = 0.f, dF4 = 0.f;                  // slope rate (2nd-order predictor)

    const int nblk = (N + 127) >> 7;
    const int gInt = (N >= 256) ? (((N - 256) >> 7) + 1) : 0; // unclamped blocks

    for (int g = 0; g < nblk; ++g) {
        const int base = g << 7;
        const int nb = base + 128;

        // prefetch next block's t (lands during the sweeps)
        float ptq, ptq1, pt0;
        if (g < gInt) {
            ptq  = trp[nb + q];
            ptq1 = trp[nb + q + 1];
            pt0  = trp[nb];
        } else {
            ptq  = trp[min(nb + q, N)];
            ptq1 = trp[min(nb + q + 1, N)];
            pt0  = trp[min(nb, N)];
        }

        const float hj = tq1 - tq;               // 0 on clamped lanes
        v2f bwt[5];
#pragma unroll
        for (int i = 0; i < 5; ++i) bwt[i] = w0k[i] * tq + bw[i];

        // 2nd-order predictor: z = y0 + dt*(F_prev + 0.5*dt*dF)
        const float dt = tq - t0;
        float z3 = fmaf(dt, fmaf(0.5f * dt, dF3, F3p), y03);
        float z4 = fmaf(dt, fmaf(0.5f * dt, dF4, F4p), y04);

        float Sg3 = 0.f, Sg4 = 0.f, F3 = 0.f, F4 = 0.f;
#pragma unroll
        for (int m = 0; m < NSWEEP; ++m) {
            v2f Fa = {c3, 0.f}, Fb = {c4, 0.f};
#pragma unroll
            for (int i = 0; i < 5; ++i) {
                v2f x = w3k[i] * z3 + (w4k[i] * z4 + bwt[i]);
                v2f e; e.x = __builtin_amdgcn_exp2f(x.x);
                       e.y = __builtin_amdgcn_exp2f(x.y);
                v2f A = e + 1.0f;
                v2f s; s.x = __builtin_amdgcn_rcpf(A.x);
                       s.y = __builtin_amdgcn_rcpf(A.y);
                Fa += wa[i] * s;
                Fb += wb[i] * s;
            }
            F3 = Fa.x + Fa.y; F4 = Fb.x + Fb.y;
            float d3 = hj * F3, d4 = hj * F4;
            float Sl3 = scan64(d3);              // within-wave inclusive prefix
            float Sl4 = scan64(d4);
            if (tid == 63) { s_tot[m][0] = Sl3; s_tot[m][1] = Sl4; }
            __syncthreads();
            // wave 1 adds wave 0's total -> full 128-step prefix
            Sg3 = Sl3 + (w ? s_tot[m][0] : 0.f);
            Sg4 = Sl4 + (w ? s_tot[m][1] : 0.f);
            if (m < NSWEEP - 1) {
                z3 = y03 + (Sg3 - d3);           // exclusive prefix -> state at step q
                z4 = y04 + (Sg4 - d4);
            }
        }

        // lane q holds the state AFTER step base+q
        if (base + q < N)
            orow[base + q + 1] = make_float2(y03 + Sg3, y04 + Sg4);

        // carry: step-127 state/slope published by wave 1
        if (w == 1) {
            float cS3 = rdl63(Sg3), cS4 = rdl63(Sg4);
            float cF3 = rdl63(F3),  cF4 = rdl63(F4);
            if (tid == 64) {
                s_carry[0] = cS3; s_carry[1] = cS4;
                s_carry[2] = cF3; s_carry[3] = cF4;
            }
        }
        __syncthreads();
        float F3n = s_carry[2];
        float F4n = s_carry[3];
        y03 += s_carry[0];
        y04 += s_carry[1];
        float span = pt0 - t0;
        float inv = (span > 0.f) ? __builtin_amdgcn_rcpf(span) : 0.f;
        dF3 = (F3n - F3p) * inv;
        dF4 = (F4n - F4p) * inv;
        F3p = F3n; F4p = F4n;

        tq = ptq; tq1 = ptq1; t0 = pt0;
        // note: next block's s_tot/s_carry writes are separated from this
        // block's reads by the sweep-0 barrier of the next iteration.
    }
}

extern "C" void kernel_launch(void* const* d_in, const int* in_sizes, int n_in,
                              void* d_out, int out_size, void* d_ws, size_t ws_size,
                              hipStream_t stream) {
    const float* thr = (const float*)d_in[0];
    const float* DOD = (const float*)d_in[1];
    const float* Vav = (const float*)d_in[2];
    const float* C0  = (const float*)d_in[3];
    const float* R0  = (const float*)d_in[4];
    const float* W1  = (const float*)d_in[5];
    const float* b1  = (const float*)d_in[6];
    const float* W2  = (const float*)d_in[7];
    const float* b2  = (const float*)d_in[8];
    float* out = (float*)d_out;

    int B = in_sizes[1];             // DOD is (1,B)
    int N = in_sizes[0] / B - 1;     // throughput is (B, N+1)

    dim3 block(128);
    dim3 grid(B);                    // 1 row per 2-wave workgroup
    ode_wf128<<<grid, block, 0, stream>>>(thr, DOD, Vav, C0, R0,
                                          W1, b1, W2, b2, out, B, N);
}

// Round 12
// 198.613 us; speedup vs baseline: 1.1236x; 1.1236x over previous
//
#include <hip/hip_runtime.h>

#define NSWEEP 2

typedef float v2f __attribute__((ext_vector_type(2)));

// Canonical wave64 inclusive prefix-sum (AMD GCN scan sequence).
__device__ __forceinline__ float scan64(float d) {
    d += __int_as_float(__builtin_amdgcn_update_dpp(0, __float_as_int(d), 0x111, 0xF, 0xF, true));
    d += __int_as_float(__builtin_amdgcn_update_dpp(0, __float_as_int(d), 0x112, 0xF, 0xF, true));
    d += __int_as_float(__builtin_amdgcn_update_dpp(0, __float_as_int(d), 0x114, 0xF, 0xF, true));
    d += __int_as_float(__builtin_amdgcn_update_dpp(0, __float_as_int(d), 0x118, 0xF, 0xF, true));
    d += __int_as_float(__builtin_amdgcn_update_dpp(0, __float_as_int(d), 0x142, 0xA, 0xF, true));
    d += __int_as_float(__builtin_amdgcn_update_dpp(0, __float_as_int(d), 0x143, 0xC, 0xF, true));
    return d;
}

// wave-uniform broadcast of lane 63 (no LDS round-trip)
__device__ __forceinline__ float rdl63(float v) {
    return __int_as_float(__builtin_amdgcn_readlane(__float_as_int(v), 63));
}
// force a wave-uniform value into an SGPR (frees a VGPR)
__device__ __forceinline__ float rfl(float v) {
    return __int_as_float(__builtin_amdgcn_readfirstlane(__float_as_int(v)));
}

__global__ __launch_bounds__(128, 8) void ode_wf128(
    const float* __restrict__ thr,   // B x (N+1)
    const float* __restrict__ DOD,   // B
    const float* __restrict__ Vav,   // B
    const float* __restrict__ C0,    // B
    const float* __restrict__ R0,    // B
    const float* __restrict__ W1,    // 10 x 5
    const float* __restrict__ b1,    // 10
    const float* __restrict__ W2,    // 5 x 10
    const float* __restrict__ b2,    // 5
    float* __restrict__ out,         // B x (N+1) x 2
    int B, int N)
{
    const int tid = threadIdx.x;        // 0..127
    const int w   = tid >> 6;           // wave id: lower/upper 64 steps
    const int q   = tid;                // step-slot within a 128-step block
    const int row = blockIdx.x;         // 1 row per 2-wave workgroup
    if (row >= B) return;               // uniform per workgroup

    __shared__ float s_tot[NSWEEP][2];  // wave0 scan totals, per sweep
    __shared__ float s_carry[4];        // wave1 -> all: S3g,S4g,F3,F4 at step 127

    // tanh(p) = 1 - 2/(1+e^{2p}); fold 2*log2(e) into layer-1 so exp2 applies
    // directly, fold "+1" into c3/c4 and "-2" into wa/wb. Hidden units packed
    // (h, h+5) -> v_pk_* fp32. ALL weights are wave-uniform: readfirstlane
    // pins them to SGPRs (VOP3P takes an SGPR pair as one operand), keeping
    // per-lane VGPR count under the 64-VGPR / 8-waves-per-SIMD tier.
    const float k2 = 2.0f * 1.4426950408889634f;
    const float dod = DOD[row], vav = Vav[row];

    v2f bw[5], w0k[5], w3k[5], w4k[5], wa[5], wb[5];   // SGPR-resident
    float c3 = b2[3], c4 = b2[4];
#pragma unroll
    for (int i = 0; i < 5; ++i) {
#pragma unroll
        for (int p = 0; p < 2; ++p) {
            int h = i + 5 * p;
            float a0 = W1[h * 5 + 0];
            float a1 = W1[h * 5 + 1];
            float a2 = W1[h * 5 + 2];
            float a3 = W1[h * 5 + 3];
            float a4 = W1[h * 5 + 4];
            bw[i][p]  = rfl(k2 * (b1[h] + a1 * dod + a2 * vav));
            w0k[i][p] = rfl(k2 * a0);
            w3k[i][p] = rfl(k2 * a3);
            w4k[i][p] = rfl(k2 * a4);
            float v3 = W2[30 + h];
            float v4 = W2[40 + h];
            c3 += v3; c4 += v4;
            wa[i][p] = rfl(-2.0f * v3);
            wb[i][p] = rfl(-2.0f * v4);
        }
    }
    c3 = rfl(c3); c4 = rfl(c4);

    float y03 = C0[row], y04 = R0[row];          // state entering current block
    const float* trp = thr + (size_t)row * (size_t)(N + 1);
    float2* orow = (float2*)(out + (size_t)row * (size_t)(N + 1) * 2);
    if (tid == 0) orow[0] = make_float2(y03, y04);

    // t for block 0 (coalesced across the workgroup) + block-base t
    float tq  = trp[min(q, N)];
    float tq1 = trp[min(q + 1, N)];
    float t0  = rfl(trp[0]);

    // bootstrap slope F(y0, t0) — uniform across all 128 lanes
    float F3p, F4p;
    {
        v2f Fa = {c3, 0.f}, Fb = {c4, 0.f};
#pragma unroll
        for (int i = 0; i < 5; ++i) {
            v2f x = w3k[i] * y03 + (w4k[i] * y04 + (w0k[i] * t0 + bw[i]));
            v2f e; e.x = __builtin_amdgcn_exp2f(x.x); e.y = __builtin_amdgcn_exp2f(x.y);
            v2f A = e + 1.0f;
            v2f s; s.x = __builtin_amdgcn_rcpf(A.x); s.y = __builtin_amdgcn_rcpf(A.y);
            Fa += wa[i] * s;
            Fb += wb[i] * s;
        }
        F3p = Fa.x + Fa.y; F4p = Fb.x + Fb.y;
    }
    float dF3 = 0.f, dF4 = 0.f;                  // slope rate (2nd-order predictor)

    const int nblk = (N + 127) >> 7;
    const int gInt = (N >= 256) ? (((N - 256) >> 7) + 1) : 0; // unclamped blocks

    for (int g = 0; g < nblk; ++g) {
        const int base = g << 7;
        const int nb = base + 128;

        // prefetch next block's t (lands during the sweeps)
        float ptq, ptq1, pt0;
        if (g < gInt) {
            ptq  = trp[nb + q];
            ptq1 = trp[nb + q + 1];
            pt0  = trp[nb];
        } else {
            ptq  = trp[min(nb + q, N)];
            ptq1 = trp[min(nb + q + 1, N)];
            pt0  = trp[min(nb, N)];
        }

        const float hj = tq1 - tq;               // 0 on clamped lanes
        v2f bwt[5];
#pragma unroll
        for (int i = 0; i < 5; ++i) bwt[i] = w0k[i] * tq + bw[i];

        // 2nd-order predictor: z = y0 + dt*(F_prev + 0.5*dt*dF)
        const float dt = tq - t0;
        float z3 = fmaf(dt, fmaf(0.5f * dt, dF3, F3p), y03);
        float z4 = fmaf(dt, fmaf(0.5f * dt, dF4, F4p), y04);

        float Sg3 = 0.f, Sg4 = 0.f, F3 = 0.f, F4 = 0.f;
#pragma unroll
        for (int m = 0; m < NSWEEP; ++m) {
            v2f Fa = {c3, 0.f}, Fb = {c4, 0.f};
#pragma unroll
            for (int i = 0; i < 5; ++i) {
                v2f x = w3k[i] * z3 + (w4k[i] * z4 + bwt[i]);
                v2f e; e.x = __builtin_amdgcn_exp2f(x.x);
                       e.y = __builtin_amdgcn_exp2f(x.y);
                v2f A = e + 1.0f;
                v2f s; s.x = __builtin_amdgcn_rcpf(A.x);
                       s.y = __builtin_amdgcn_rcpf(A.y);
                Fa += wa[i] * s;
                Fb += wb[i] * s;
            }
            F3 = Fa.x + Fa.y; F4 = Fb.x + Fb.y;
            float d3 = hj * F3, d4 = hj * F4;
            float Sl3 = scan64(d3);              // within-wave inclusive prefix
            float Sl4 = scan64(d4);
            if (tid == 63) { s_tot[m][0] = Sl3; s_tot[m][1] = Sl4; }
            __syncthreads();
            // wave 1 adds wave 0's total -> full 128-step prefix
            Sg3 = Sl3 + (w ? s_tot[m][0] : 0.f);
            Sg4 = Sl4 + (w ? s_tot[m][1] : 0.f);
            if (m < NSWEEP - 1) {
                z3 = y03 + (Sg3 - d3);           // exclusive prefix -> state at step q
                z4 = y04 + (Sg4 - d4);
            }
        }

        // lane q holds the state AFTER step base+q
        if (base + q < N)
            orow[base + q + 1] = make_float2(y03 + Sg3, y04 + Sg4);

        // carry: step-127 state/slope published by wave 1
        if (w == 1) {
            float cS3 = rdl63(Sg3), cS4 = rdl63(Sg4);
            float cF3 = rdl63(F3),  cF4 = rdl63(F4);
            if (tid == 64) {
                s_carry[0] = cS3; s_carry[1] = cS4;
                s_carry[2] = cF3; s_carry[3] = cF4;
            }
        }
        __syncthreads();
        float F3n = s_carry[2];
        float F4n = s_carry[3];
        y03 += s_carry[0];
        y04 += s_carry[1];
        pt0 = rfl(pt0);
        float span = pt0 - t0;
        float inv = (span > 0.f) ? __builtin_amdgcn_rcpf(span) : 0.f;
        dF3 = (F3n - F3p) * inv;
        dF4 = (F4n - F4p) * inv;
        F3p = F3n; F4p = F4n;

        tq = ptq; tq1 = ptq1; t0 = pt0;
        // next block's s_tot/s_carry writes are separated from this block's
        // reads by the sweep-0 barrier of the next iteration.
    }
}

extern "C" void kernel_launch(void* const* d_in, const int* in_sizes, int n_in,
                              void* d_out, int out_size, void* d_ws, size_t ws_size,
                              hipStream_t stream) {
    const float* thr = (const float*)d_in[0];
    const float* DOD = (const float*)d_in[1];
    const float* Vav = (const float*)d_in[2];
    const float* C0  = (const float*)d_in[3];
    const float* R0  = (const float*)d_in[4];
    const float* W1  = (const float*)d_in[5];
    const float* b1  = (const float*)d_in[6];
    const float* W2  = (const float*)d_in[7];
    const float* b2  = (const float*)d_in[8];
    float* out = (float*)d_out;

    int B = in_sizes[1];             // DOD is (1,B)
    int N = in_sizes[0] / B - 1;     // throughput is (B, N+1)

    dim3 block(128);
    dim3 grid(B);                    // 1 row per 2-wave workgroup
    ode_wf128<<<grid, block, 0, stream>>>(thr, DOD, Vav, C0, R0,
                                          W1, b1, W2, b2, out, B, N);
}

// Round 13
// 69.025 us; speedup vs baseline: 3.2329x; 2.8774x over previous
//
#include <hip/hip_runtime.h>

#define NSWEEP 2

typedef float v2f __attribute__((ext_vector_type(2)));

// Canonical wave64 inclusive prefix-sum (AMD GCN scan sequence).
__device__ __forceinline__ float scan64(float d) {
    d += __int_as_float(__builtin_amdgcn_update_dpp(0, __float_as_int(d), 0x111, 0xF, 0xF, true));
    d += __int_as_float(__builtin_amdgcn_update_dpp(0, __float_as_int(d), 0x112, 0xF, 0xF, true));
    d += __int_as_float(__builtin_amdgcn_update_dpp(0, __float_as_int(d), 0x114, 0xF, 0xF, true));
    d += __int_as_float(__builtin_amdgcn_update_dpp(0, __float_as_int(d), 0x118, 0xF, 0xF, true));
    d += __int_as_float(__builtin_amdgcn_update_dpp(0, __float_as_int(d), 0x142, 0xA, 0xF, true));
    d += __int_as_float(__builtin_amdgcn_update_dpp(0, __float_as_int(d), 0x143, 0xC, 0xF, true));
    return d;
}

// wave-uniform broadcast of lane 63 (no LDS round-trip)
__device__ __forceinline__ float rdl63(float v) {
    return __int_as_float(__builtin_amdgcn_readlane(__float_as_int(v), 63));
}
// force a wave-uniform value into an SGPR (frees a VGPR)
__device__ __forceinline__ float rfl(float v) {
    return __int_as_float(__builtin_amdgcn_readfirstlane(__float_as_int(v)));
}

// launch_bounds note: (128, 8) forced a 32-VGPR budget -> catastrophic spill
// (rounds 11/12: FETCH 500+ MB, dur 200us). (128, 4) gives the allocator a
// 128-VGPR budget; with weights SGPR-pinned the kernel allocates ~<64 and the
// hardware still reaches 8 waves/SIMD based on ACTUAL usage.
__global__ __launch_bounds__(128, 4) void ode_wf128(
    const float* __restrict__ thr,   // B x (N+1)
    const float* __restrict__ DOD,   // B
    const float* __restrict__ Vav,   // B
    const float* __restrict__ C0,    // B
    const float* __restrict__ R0,    // B
    const float* __restrict__ W1,    // 10 x 5
    const float* __restrict__ b1,    // 10
    const float* __restrict__ W2,    // 5 x 10
    const float* __restrict__ b2,    // 5
    float* __restrict__ out,         // B x (N+1) x 2
    int B, int N)
{
    const int tid = threadIdx.x;        // 0..127
    const int w   = tid >> 6;           // wave id: lower/upper 64 steps
    const int q   = tid;                // step-slot within a 128-step block
    const int row = blockIdx.x;         // 1 row per 2-wave workgroup
    if (row >= B) return;               // uniform per workgroup

    __shared__ float s_tot[NSWEEP][2];  // wave0 scan totals, per sweep
    __shared__ float s_carry[4];        // wave1 -> all: S3g,S4g,F3,F4 at step 127

    // tanh(p) = 1 - 2/(1+e^{2p}); fold 2*log2(e) into layer-1 so exp2 applies
    // directly, fold "+1" into c3/c4 and "-2" into wa/wb. Hidden units packed
    // (h, h+5) -> v_pk_* fp32. Weights are wave-uniform: readfirstlane pins
    // them to SGPRs, keeping per-lane VGPR use in the 8-waves/SIMD tier.
    const float k2 = 2.0f * 1.4426950408889634f;
    const float dod = DOD[row], vav = Vav[row];

    v2f bw[5], w0k[5], w3k[5], w4k[5], wa[5], wb[5];   // SGPR-resident
    float c3 = b2[3], c4 = b2[4];
#pragma unroll
    for (int i = 0; i < 5; ++i) {
#pragma unroll
        for (int p = 0; p < 2; ++p) {
            int h = i + 5 * p;
            float a0 = W1[h * 5 + 0];
            float a1 = W1[h * 5 + 1];
            float a2 = W1[h * 5 + 2];
            float a3 = W1[h * 5 + 3];
            float a4 = W1[h * 5 + 4];
            bw[i][p]  = rfl(k2 * (b1[h] + a1 * dod + a2 * vav));
            w0k[i][p] = rfl(k2 * a0);
            w3k[i][p] = rfl(k2 * a3);
            w4k[i][p] = rfl(k2 * a4);
            float v3 = W2[30 + h];
            float v4 = W2[40 + h];
            c3 += v3; c4 += v4;
            wa[i][p] = rfl(-2.0f * v3);
            wb[i][p] = rfl(-2.0f * v4);
        }
    }
    c3 = rfl(c3); c4 = rfl(c4);

    float y03 = C0[row], y04 = R0[row];          // state entering current block
    const float* trp = thr + (size_t)row * (size_t)(N + 1);
    float2* orow = (float2*)(out + (size_t)row * (size_t)(N + 1) * 2);
    if (tid == 0) orow[0] = make_float2(y03, y04);

    // t for block 0 (coalesced across the workgroup) + block-base t
    float tq  = trp[min(q, N)];
    float tq1 = trp[min(q + 1, N)];
    float t0  = rfl(trp[0]);

    // bootstrap slope F(y0, t0) — uniform across all 128 lanes
    float F3p, F4p;
    {
        v2f Fa = {c3, 0.f}, Fb = {c4, 0.f};
#pragma unroll
        for (int i = 0; i < 5; ++i) {
            v2f x = w3k[i] * y03 + (w4k[i] * y04 + (w0k[i] * t0 + bw[i]));
            v2f e; e.x = __builtin_amdgcn_exp2f(x.x); e.y = __builtin_amdgcn_exp2f(x.y);
            v2f A = e + 1.0f;
            v2f s; s.x = __builtin_amdgcn_rcpf(A.x); s.y = __builtin_amdgcn_rcpf(A.y);
            Fa += wa[i] * s;
            Fb += wb[i] * s;
        }
        F3p = Fa.x + Fa.y; F4p = Fb.x + Fb.y;
    }
    float dF3 = 0.f, dF4 = 0.f;                  // slope rate (2nd-order predictor)

    const int nblk = (N + 127) >> 7;
    const int gInt = (N >= 256) ? (((N - 256) >> 7) + 1) : 0; // unclamped blocks

    for (int g = 0; g < nblk; ++g) {
        const int base = g << 7;
        const int nb = base + 128;

        // prefetch next block's t (lands during the sweeps)
        float ptq, ptq1, pt0;
        if (g < gInt) {
            ptq  = trp[nb + q];
            ptq1 = trp[nb + q + 1];
            pt0  = trp[nb];
        } else {
            ptq  = trp[min(nb + q, N)];
            ptq1 = trp[min(nb + q + 1, N)];
            pt0  = trp[min(nb, N)];
        }

        const float hj = tq1 - tq;               // 0 on clamped lanes
        v2f bwt[5];
#pragma unroll
        for (int i = 0; i < 5; ++i) bwt[i] = w0k[i] * tq + bw[i];

        // 2nd-order predictor: z = y0 + dt*(F_prev + 0.5*dt*dF)
        const float dt = tq - t0;
        float z3 = fmaf(dt, fmaf(0.5f * dt, dF3, F3p), y03);
        float z4 = fmaf(dt, fmaf(0.5f * dt, dF4, F4p), y04);

        float Sg3 = 0.f, Sg4 = 0.f, F3 = 0.f, F4 = 0.f;
#pragma unroll
        for (int m = 0; m < NSWEEP; ++m) {
            v2f Fa = {c3, 0.f}, Fb = {c4, 0.f};
#pragma unroll
            for (int i = 0; i < 5; ++i) {
                v2f x = w3k[i] * z3 + (w4k[i] * z4 + bwt[i]);
                v2f e; e.x = __builtin_amdgcn_exp2f(x.x);
                       e.y = __builtin_amdgcn_exp2f(x.y);
                v2f A = e + 1.0f;
                v2f s; s.x = __builtin_amdgcn_rcpf(A.x);
                       s.y = __builtin_amdgcn_rcpf(A.y);
                Fa += wa[i] * s;
                Fb += wb[i] * s;
            }
            F3 = Fa.x + Fa.y; F4 = Fb.x + Fb.y;
            float d3 = hj * F3, d4 = hj * F4;
            float Sl3 = scan64(d3);              // within-wave inclusive prefix
            float Sl4 = scan64(d4);
            if (tid == 63) { s_tot[m][0] = Sl3; s_tot[m][1] = Sl4; }
            __syncthreads();
            // wave 1 adds wave 0's total -> full 128-step prefix
            Sg3 = Sl3 + (w ? s_tot[m][0] : 0.f);
            Sg4 = Sl4 + (w ? s_tot[m][1] : 0.f);
            if (m < NSWEEP - 1) {
                z3 = y03 + (Sg3 - d3);           // exclusive prefix -> state at step q
                z4 = y04 + (Sg4 - d4);
            }
        }

        // lane q holds the state AFTER step base+q
        if (base + q < N)
            orow[base + q + 1] = make_float2(y03 + Sg3, y04 + Sg4);

        // carry: step-127 state/slope published by wave 1
        if (w == 1) {
            float cS3 = rdl63(Sg3), cS4 = rdl63(Sg4);
            float cF3 = rdl63(F3),  cF4 = rdl63(F4);
            if (tid == 64) {
                s_carry[0] = cS3; s_carry[1] = cS4;
                s_carry[2] = cF3; s_carry[3] = cF4;
            }
        }
        __syncthreads();
        float F3n = s_carry[2];
        float F4n = s_carry[3];
        y03 += s_carry[0];
        y04 += s_carry[1];
        pt0 = rfl(pt0);
        float span = pt0 - t0;
        float inv = (span > 0.f) ? __builtin_amdgcn_rcpf(span) : 0.f;
        dF3 = (F3n - F3p) * inv;
        dF4 = (F4n - F4p) * inv;
        F3p = F3n; F4p = F4n;

        tq = ptq; tq1 = ptq1; t0 = pt0;
        // next block's s_tot/s_carry writes are separated from this block's
        // reads by the sweep-0 barrier of the next iteration.
    }
}

extern "C" void kernel_launch(void* const* d_in, const int* in_sizes, int n_in,
                              void* d_out, int out_size, void* d_ws, size_t ws_size,
                              hipStream_t stream) {
    const float* thr = (const float*)d_in[0];
    const float* DOD = (const float*)d_in[1];
    const float* Vav = (const float*)d_in[2];
    const float* C0  = (const float*)d_in[3];
    const float* R0  = (const float*)d_in[4];
    const float* W1  = (const float*)d_in[5];
    const float* b1  = (const float*)d_in[6];
    const float* W2  = (const float*)d_in[7];
    const float* b2  = (const float*)d_in[8];
    float* out = (float*)d_out;

    int B = in_sizes[1];             // DOD is (1,B)
    int N = in_sizes[0] / B - 1;     // throughput is (B, N+1)

    dim3 block(128);
    dim3 grid(B);                    // 1 row per 2-wave workgroup
    ode_wf128<<<grid, block, 0, stream>>>(thr, DOD, Vav, C0, R0,
                                          W1, b1, W2, b2, out, B, N);
}

// Round 14
// 58.102 us; speedup vs baseline: 3.8407x; 1.1880x over previous
//
#include <hip/hip_runtime.h>

typedef float v2f __attribute__((ext_vector_type(2)));

// Canonical wave64 inclusive prefix-sum (AMD GCN scan sequence).
__device__ __forceinline__ float scan64(float d) {
    d += __int_as_float(__builtin_amdgcn_update_dpp(0, __float_as_int(d), 0x111, 0xF, 0xF, true));
    d += __int_as_float(__builtin_amdgcn_update_dpp(0, __float_as_int(d), 0x112, 0xF, 0xF, true));
    d += __int_as_float(__builtin_amdgcn_update_dpp(0, __float_as_int(d), 0x114, 0xF, 0xF, true));
    d += __int_as_float(__builtin_amdgcn_update_dpp(0, __float_as_int(d), 0x118, 0xF, 0xF, true));
    d += __int_as_float(__builtin_amdgcn_update_dpp(0, __float_as_int(d), 0x142, 0xA, 0xF, true));
    d += __int_as_float(__builtin_amdgcn_update_dpp(0, __float_as_int(d), 0x143, 0xC, 0xF, true));
    return d;
}

// wave-uniform broadcast of lane 63 (no LDS round-trip)
__device__ __forceinline__ float rdl63(float v) {
    return __int_as_float(__builtin_amdgcn_readlane(__float_as_int(v), 63));
}

// Round-9 skeleton (64-step blocks, 1 row/wave, barrier-free) + linearized
// second sweep: F(z2) ~= F(z1) + J.dz reusing s from sweep 1 (ds/dx =
// -ln2*s*(1-s) for s = 1/(1+2^x)) -> sweep 2 has ZERO transcendentals.
__global__ __launch_bounds__(64, 4) void ode_wf64lin(
    const float* __restrict__ thr,   // B x (N+1)
    const float* __restrict__ DOD,   // B
    const float* __restrict__ Vav,   // B
    const float* __restrict__ C0,    // B
    const float* __restrict__ R0,    // B
    const float* __restrict__ W1,    // 10 x 5
    const float* __restrict__ b1,    // 10
    const float* __restrict__ W2,    // 5 x 10
    const float* __restrict__ b2,    // 5
    float* __restrict__ out,         // B x (N+1) x 2
    int B, int N)
{
    const int j   = threadIdx.x & 63;   // step-slot within a 64-step block
    const int row = blockIdx.x;         // 1 row per wave
    if (row >= B) return;

    // tanh(p) = 1 - 2/(1+e^{2p}); fold 2*log2(e) into layer-1 so exp2 applies
    // directly, fold "+1" into c3/c4 and "-2" into wa/wb. Hidden units packed
    // (h, h+5) -> v_pk_* fp32.
    const float k2  = 2.0f * 1.4426950408889634f;
    const float ln2 = 0.6931471805599453f;
    const float dod = DOD[row], vav = Vav[row];

    v2f bw[5], w0k[5], w3k[5], w4k[5], wa[5], wb[5];
    float c3 = b2[3], c4 = b2[4];
#pragma unroll
    for (int i = 0; i < 5; ++i) {
#pragma unroll
        for (int p = 0; p < 2; ++p) {
            int h = i + 5 * p;
            float a0 = W1[h * 5 + 0];
            float a1 = W1[h * 5 + 1];
            float a2 = W1[h * 5 + 2];
            float a3 = W1[h * 5 + 3];
            float a4 = W1[h * 5 + 4];
            bw[i][p]  = k2 * (b1[h] + a1 * dod + a2 * vav);
            w0k[i][p] = k2 * a0;
            w3k[i][p] = k2 * a3;
            w4k[i][p] = k2 * a4;
            float v3 = W2[30 + h];
            float v4 = W2[40 + h];
            c3 += v3; c4 += v4;
            wa[i][p] = -2.0f * v3;
            wb[i][p] = -2.0f * v4;
        }
    }

    float y03 = C0[row], y04 = R0[row];          // state entering current block
    const float* trp = thr + (size_t)row * (size_t)(N + 1);
    float2* orow = (float2*)(out + (size_t)row * (size_t)(N + 1) * 2);
    if (j == 0) orow[0] = make_float2(y03, y04);

    // t for block 0 (coalesced across the wave) + block-base t
    float tj  = trp[min(j, N)];
    float tj1 = trp[min(j + 1, N)];
    float t0  = trp[0];

    // bootstrap slope F(y0, t0) — uniform across the wave
    float F3p, F4p;
    {
        v2f Fa = {c3, 0.f}, Fb = {c4, 0.f};
#pragma unroll
        for (int i = 0; i < 5; ++i) {
            v2f x = w3k[i] * y03 + (w4k[i] * y04 + (w0k[i] * t0 + bw[i]));
            v2f e; e.x = __builtin_amdgcn_exp2f(x.x); e.y = __builtin_amdgcn_exp2f(x.y);
            v2f A = e + 1.0f;
            v2f s; s.x = __builtin_amdgcn_rcpf(A.x); s.y = __builtin_amdgcn_rcpf(A.y);
            Fa += wa[i] * s;
            Fb += wb[i] * s;
        }
        F3p = Fa.x + Fa.y; F4p = Fb.x + Fb.y;
    }
    float dF3 = 0.f, dF4 = 0.f;                  // slope rate (2nd-order predictor)

    const int nblk = (N + 63) >> 6;
    const int gInt = max(0, (N + 1) / 64 - 1);   // blocks with unclamped loads/stores

    for (int g = 0; g < nblk; ++g) {
        const int base = g << 6;
        const int nb = base + 64;

        // prefetch next block's t (lands during the sweeps)
        float ptj, ptj1, pt0;
        if (g < gInt) {
            ptj  = trp[nb + j];
            ptj1 = trp[nb + j + 1];
            pt0  = trp[nb];
        } else {
            ptj  = trp[min(nb + j, N)];
            ptj1 = trp[min(nb + j + 1, N)];
            pt0  = trp[min(nb, N)];
        }

        const float hj = tj1 - tj;               // 0 on clamped lanes
        v2f bwt[5];
#pragma unroll
        for (int i = 0; i < 5; ++i) bwt[i] = w0k[i] * tj + bw[i];

        // 2nd-order predictor: z = y0 + dt*(F_prev + 0.5*dt*dF)
        const float dt = tj - t0;
        float z3 = fmaf(dt, fmaf(0.5f * dt, dF3, F3p), y03);
        float z4 = fmaf(dt, fmaf(0.5f * dt, dF4, F4p), y04);

        // ---- sweep 1: full MLP eval at z1 (keep s for the Jacobian) ----
        v2f sv[5];
        float F3, F4;
        {
            v2f Fa = {c3, 0.f}, Fb = {c4, 0.f};
#pragma unroll
            for (int i = 0; i < 5; ++i) {
                v2f x = w3k[i] * z3 + (w4k[i] * z4 + bwt[i]);
                v2f e; e.x = __builtin_amdgcn_exp2f(x.x);
                       e.y = __builtin_amdgcn_exp2f(x.y);
                v2f A = e + 1.0f;
                v2f s; s.x = __builtin_amdgcn_rcpf(A.x);
                       s.y = __builtin_amdgcn_rcpf(A.y);
                sv[i] = s;
                Fa += wa[i] * s;
                Fb += wb[i] * s;
            }
            F3 = Fa.x + Fa.y; F4 = Fb.x + Fb.y;
        }
        float d3 = hj * F3, d4 = hj * F4;
        float S3 = scan64(d3);
        float S4 = scan64(d4);
        // corrected state at step j (exclusive prefix)
        float dz3 = (y03 + (S3 - d3)) - z3;
        float dz4 = (y04 + (S4 - d4)) - z4;

        // ---- sweep 2: linearized, zero transcendentals ----
        // ds = -ln2 * s*(1-s) * dx,  dx = w3k*dz3 + w4k*dz4
        float F3b, F4b;
        {
            v2f acc3 = {0.f, 0.f}, acc4 = {0.f, 0.f};
#pragma unroll
            for (int i = 0; i < 5; ++i) {
                v2f dx = w3k[i] * dz3 + w4k[i] * dz4;
                v2f s  = sv[i];
                v2f t  = s - s * s;              // s*(1-s)
                v2f u  = dx * t;
                acc3 += wa[i] * u;
                acc4 += wb[i] * u;
            }
            F3b = fmaf(-ln2, acc3.x + acc3.y, F3);
            F4b = fmaf(-ln2, acc4.x + acc4.y, F4);
        }
        d3 = hj * F3b; d4 = hj * F4b;
        S3 = scan64(d3);
        S4 = scan64(d4);

        // lane j holds the state AFTER step base+j
        if (g < gInt || base + j < N)
            orow[base + j + 1] = make_float2(y03 + S3, y04 + S4);

        // carry via readlane (wave-uniform, no LDS latency on the serial path)
        float F3n = rdl63(F3b);
        float F4n = rdl63(F4b);
        y03 += rdl63(S3);
        y04 += rdl63(S4);
        float span = pt0 - t0;
        float inv = (span > 0.f) ? __builtin_amdgcn_rcpf(span) : 0.f;
        dF3 = (F3n - F3p) * inv;
        dF4 = (F4n - F4p) * inv;
        F3p = F3n; F4p = F4n;

        tj = ptj; tj1 = ptj1; t0 = pt0;
    }
}

extern "C" void kernel_launch(void* const* d_in, const int* in_sizes, int n_in,
                              void* d_out, int out_size, void* d_ws, size_t ws_size,
                              hipStream_t stream) {
    const float* thr = (const float*)d_in[0];
    const float* DOD = (const float*)d_in[1];
    const float* Vav = (const float*)d_in[2];
    const float* C0  = (const float*)d_in[3];
    const float* R0  = (const float*)d_in[4];
    const float* W1  = (const float*)d_in[5];
    const float* b1  = (const float*)d_in[6];
    const float* W2  = (const float*)d_in[7];
    const float* b2  = (const float*)d_in[8];
    float* out = (float*)d_out;

    int B = in_sizes[1];             // DOD is (1,B)
    int N = in_sizes[0] / B - 1;     // throughput is (B, N+1)

    dim3 block(64);
    dim3 grid(B);                    // 1 row per 64-thread wave
    ode_wf64lin<<<grid, block, 0, stream>>>(thr, DOD, Vav, C0, R0,
                                            W1, b1, W2, b2, out, B, N);
}